// Round 12
// baseline (77.428 us; speedup 1.0000x reference)
//
#include <hip/hip_runtime.h>
#include <cstddef>

typedef _Float16 h2    __attribute__((ext_vector_type(2)));
typedef _Float16 half8 __attribute__((ext_vector_type(8)));
typedef float    f32x4 __attribute__((ext_vector_type(4)));
typedef float    f32x2 __attribute__((ext_vector_type(2)));

#define CH    192
#define CWID  640
#define IMG_H 384
#define IMG_W 1280
#define TW    128
#define GR    224      // g rows staged
#define RAWC  179      // 66 fl cols + 113 g cols

__device__ __forceinline__ float fastrcp(float x) {
#if __has_builtin(__builtin_amdgcn_rcpf)
  return __builtin_amdgcn_rcpf(x);
#else
  return 1.0f / x;
#endif
}
__device__ __forceinline__ float fastexp2(float x) {
#if __has_builtin(__builtin_amdgcn_exp2f)
  return __builtin_amdgcn_exp2f(x);
#else
  return exp2f(x);
#endif
}
// Cross-lane pair exchange (xor 16 / xor 32): permlane on gfx950 (pure VALU),
// DS fallbacks otherwise.
__device__ __forceinline__ f32x2 xsw16(float x) {
#if __has_builtin(__builtin_amdgcn_permlane16_swap)
  auto r = __builtin_amdgcn_permlane16_swap(__float_as_uint(x), __float_as_uint(x), false, false);
  f32x2 o; o.x = __uint_as_float(r[0]); o.y = __uint_as_float(r[1]); return o;
#else
  f32x2 o; o.x = x;
  o.y = __uint_as_float((unsigned)__builtin_amdgcn_ds_swizzle((int)__float_as_uint(x), 0x401F));
  return o;
#endif
}
__device__ __forceinline__ f32x2 xsw32(float x) {
#if __has_builtin(__builtin_amdgcn_permlane32_swap)
  auto r = __builtin_amdgcn_permlane32_swap(__float_as_uint(x), __float_as_uint(x), false, false);
  f32x2 o; o.x = __uint_as_float(r[0]); o.y = __uint_as_float(r[1]); return o;
#else
  const int bpa = ((threadIdx.x & 63) ^ 32) << 2;
  f32x2 o; o.x = x;
  o.y = __uint_as_float((unsigned)__builtin_amdgcn_ds_bpermute(bpa, (int)__float_as_uint(x)));
  return o;
#endif
}
// CDNA VOP3P packed-f32 — hipcc never auto-forms these.
__device__ __forceinline__ f32x2 pkadd(f32x2 a, f32x2 b) {
  f32x2 d; asm("v_pk_add_f32 %0, %1, %2" : "=v"(d) : "v"(a), "v"(b)); return d;
}
__device__ __forceinline__ f32x2 pkfma(f32x2 a, f32x2 b, f32x2 c) {
  f32x2 d; asm("v_pk_fma_f32 %0, %1, %2, %3" : "=v"(d) : "v"(a), "v"(b), "v"(c)); return d;
}
__device__ __forceinline__ float min3f(float a, float b, float c) {
  float d; asm("v_min3_f32 %0, %1, %2, %3" : "=v"(d) : "v"(a), "v"(b), "v"(c)); return d;
}
__device__ __forceinline__ float max3f(float a, float b, float c) {
  float d; asm("v_max3_f32 %0, %1, %2, %3" : "=v"(d) : "v"(a), "v"(b), "v"(c)); return d;
}
__device__ __forceinline__ f32x2 lo2(f32x4 v) { f32x2 r; r.x = v.x; r.y = v.y; return r; }
__device__ __forceinline__ f32x2 hi2(f32x4 v) { f32x2 r; r.x = v.z; r.y = v.w; return r; }

// raw LDS byte address with line-XOR swizzle: 8 consecutive t cover the 8 16B
// slots of one 128B bank-row -> conflict-free writes and strided-row reads.
__device__ __forceinline__ int rawaddr(int t) {
  return ((t >> 3) << 7) + ((((t & 7) ^ ((t >> 3) & 7))) << 4);
}

// ---------------- Kernel 1: 3x3 stride-2 SAME conv + bias + ReLU -> f16 ----------------
// VERBATIM R4 conv (measured ~18us, no scratch). R6/R7/R8 restructurings all triggered
// allocator scratch demotion of acc[32] (252MB scratch writes). Do not restructure.
__global__ __launch_bounds__(256)
void conv_relu_kernel(const float* __restrict__ xl, const float* __restrict__ xr,
                      const float* __restrict__ Wt, const float* __restrict__ bias,
                      _Float16* __restrict__ Fc) {
  __shared__ float wl[864];
  __shared__ float bl[32];
  const int tid = threadIdx.x;
  for (int t = tid; t < 864; t += 256) wl[t] = Wt[t];
  if (tid < 32) bl[tid] = bias[tid];
  __syncthreads();

  const int g  = blockIdx.x * 256 + tid;   // [0, 4*192*640)
  const int ow = g % CWID;
  const int t2 = g / CWID;
  const int oh = t2 % CH;
  const int bb = t2 / CH;
  const float* src = (bb < 2) ? (xl + (size_t)bb * IMG_H * IMG_W * 3)
                              : (xr + (size_t)(bb - 2) * IMG_H * IMG_W * 3);
  float acc[32];
  #pragma unroll
  for (int c = 0; c < 32; ++c) acc[c] = bl[c];

  #pragma unroll
  for (int kh = 0; kh < 3; ++kh) {
    const int ir = oh * 2 + kh;
    if (ir >= IMG_H) continue;
    #pragma unroll
    for (int kw = 0; kw < 3; ++kw) {
      const int ic = ow * 2 + kw;
      if (ic >= IMG_W) continue;
      const float* px = src + ((size_t)ir * IMG_W + ic) * 3;
      #pragma unroll
      for (int ci = 0; ci < 3; ++ci) {
        const float v = px[ci];
        const float* wp = &wl[((kh * 3 + kw) * 3 + ci) * 32];
        #pragma unroll
        for (int c8 = 0; c8 < 8; ++c8) {
          const float4 w4 = *(const float4*)(wp + c8 * 4);
          acc[c8 * 4 + 0] = fmaf(v, w4.x, acc[c8 * 4 + 0]);
          acc[c8 * 4 + 1] = fmaf(v, w4.y, acc[c8 * 4 + 1]);
          acc[c8 * 4 + 2] = fmaf(v, w4.z, acc[c8 * 4 + 2]);
          acc[c8 * 4 + 3] = fmaf(v, w4.w, acc[c8 * 4 + 3]);
        }
      }
    }
  }
  _Float16 hv[32];
  #pragma unroll
  for (int c = 0; c < 32; ++c) hv[c] = (_Float16)fmaxf(acc[c], 0.f);
  half8* dst = (half8*)(Fc + (size_t)g * 32);
  #pragma unroll
  for (int q = 0; q < 4; ++q) {
    half8 o;
    #pragma unroll
    for (int e = 0; e < 8; ++e) o[e] = hv[q * 8 + e];
    dst[q] = o;
  }
}

// ------- Kernel 2: f16 MFMA cost volume + soft-argmin -------
// raw staged one 16B chunk per pass (4 passes): LDS 27008B -> 6 blocks/CU, and the
// line-XOR raw layout makes all raw LDS traffic bank-conflict-free.
__global__ __launch_bounds__(256, 4)
void disparity_mfma_kernel(const _Float16* __restrict__ Fc, float* __restrict__ out) {
  __shared__ alignas(16) _Float16 raw[192 * 8];     // 3 KB: one 16B chunk, swizzled
  __shared__ alignas(16) _Float16 flH[8 * 512];     // 8 tiles [16][32] f16
  __shared__ alignas(16) _Float16 gH[14 * 512];     // 14 tiles
  __shared__ alignas(16) float As[TW];
  __shared__ alignas(16) float Bs[GR];

  const int tid = threadIdx.x;
  const int w0  = blockIdx.x * TW;
  const int h   = blockIdx.y;
  const int bz  = blockIdx.z;

  // vertical bilinear params (half-pixel, clamped)
  const int hk = h >> 1;
  int r0, r1; float wv0;
  if (h & 1) { r0 = hk; r1 = (hk + 1 > CH - 1) ? CH - 1 : hk + 1; wv0 = 0.75f; }
  else       { r0 = (hk - 1 < 0) ? 0 : hk - 1; r1 = hk;           wv0 = 0.25f; }
  const half8 w0v = (half8)(_Float16)wv0;
  const half8 w1v = (half8)(_Float16)(1.0f - wv0);

  const int vbaseL = (w0 >> 1) + 639;  // fl raw region (t 0..65)
  const int vbaseR = (w0 >> 1) + 592;  // g raw region (t 66..178)

  char* const rawB = (char*)raw;

  // scalar row bases (hoisted 64-bit math)
  const char* const bL0 = (const char*)(Fc + ((size_t)bz * CH + r0) * CWID * 32);
  const char* const bL1 = (const char*)(Fc + ((size_t)bz * CH + r1) * CWID * 32);
  const char* const bR0 = (const char*)(Fc + ((size_t)(bz + 2) * CH + r0) * CWID * 32);
  const char* const bR1 = (const char*)(Fc + ((size_t)(bz + 2) * CH + r1) * CWID * 32);

  // ---- phase-0 per-thread source pointers (t = tid), hoisted out of the pass loop ----
  const char* g0p = bL0; const char* g1p = bL1; int rawwr = 0;
  {
    const int t = (tid < RAWC) ? tid : RAWC - 1;
    const bool isfl = t < 66;
    int v = isfl ? (vbaseL + t) : (vbaseR + t - 66);   // in [592, 1280]
    v -= (v >= 640) ? 640 : 0;
    v -= (v >= 640) ? 640 : 0;                          // 1280 -> 0 (roll wrap)
    g0p = (isfl ? bL0 : bR0) + (v << 6);
    g1p = (isfl ? bL1 : bR1) + (v << 6);
    rawwr = rawaddr(t);
  }

  // ---- precompute phase-1 row params for row A = tid and row B = tid+256 ----
  const _Float16 h75 = (_Float16)0.75f, h25 = (_Float16)0.25f;
  int a_t0a, a_t1a, a_swz; half8 a_h0, a_h1; char* a_dst;
  int b_t0a, b_t1a, b_swz; half8 b_h0, b_h1; char* b_dst;
  {
    const int row = tid;
    const bool isfl = row < TW;
    const int r  = isfl ? row : row - TW;
    const int uv = isfl ? (w0 + r) : (w0 - 95 + r);
    const int uact = uv < 0 ? uv + IMG_W : (uv >= IMG_W ? uv - IMG_W : uv);
    const int up = uv + IMG_W;
    const int vm0 = (up - 1) >> 1;
    int t0 = vm0 - (isfl ? vbaseL : (vbaseR - 66));
    int t1 = t0 + 1;
    if (uact == 0)         t0 = t1;
    if (uact == IMG_W - 1) t1 = t0;
    a_h0 = (half8)((up & 1) ? h75 : h25);
    a_h1 = (half8)((up & 1) ? h25 : h75);
    a_t0a = rawaddr(t0);
    a_t1a = rawaddr(t1);
    a_swz = r & 3;
    a_dst = (char*)(isfl ? flH : gH) + (r >> 4) * 1024 + (r & 15) * 64;
  }
  {
    const int row = tid + 256;   // always a g row (256..351) when used
    const int r  = row - TW;
    const int uv = w0 - 95 + r;
    const int uact = uv < 0 ? uv + IMG_W : (uv >= IMG_W ? uv - IMG_W : uv);
    const int up = uv + IMG_W;
    const int vm0 = (up - 1) >> 1;
    int t0 = vm0 - (vbaseR - 66);
    int t1 = t0 + 1;
    if (uact == 0)         t0 = t1;
    if (uact == IMG_W - 1) t1 = t0;
    b_h0 = (half8)((up & 1) ? h75 : h25);
    b_h1 = (half8)((up & 1) ? h25 : h75);
    b_t0a = rawaddr(t0);
    b_t1a = rawaddr(t1);
    b_swz = r & 3;
    b_dst = (char*)gH + (r >> 4) * 1024 + (r & 15) * 64;
  }

  float sA = 0.f, sB = 0.f;
  #pragma unroll
  for (int pass = 0; pass < 4; ++pass) {
    // ---- Phase 0: stage chunk `pass` of all 179 raw rows + vertical blend ----
    if (tid < RAWC) {
      const half8 a0 = *(const half8*)(g0p + (pass << 4));
      const half8 a1 = *(const half8*)(g1p + (pass << 4));
      *(half8*)(rawB + rawwr) = a0 * w0v + a1 * w1v;
    }
    __syncthreads();

    // ---- Phase 1: horizontal blend + tile chunk + norm partials ----
    {
      const half8 a = *(const half8*)(rawB + a_t0a);
      const half8 b = *(const half8*)(rawB + a_t1a);
      const half8 v = a * a_h0 + b * a_h1;
      #pragma unroll
      for (int e = 0; e < 4; ++e) {
        h2 pe = {v[2 * e], v[2 * e + 1]};
#if __has_builtin(__builtin_amdgcn_fdot2)
        sA = __builtin_amdgcn_fdot2(pe, pe, sA, false);
#else
        sA += (float)pe[0] * (float)pe[0] + (float)pe[1] * (float)pe[1];
#endif
      }
      *(half8*)(a_dst + ((pass ^ a_swz) << 4)) = v;
    }
    if (tid < TW + GR - 256) {
      const half8 a = *(const half8*)(rawB + b_t0a);
      const half8 b = *(const half8*)(rawB + b_t1a);
      const half8 v = a * b_h0 + b * b_h1;
      #pragma unroll
      for (int e = 0; e < 4; ++e) {
        h2 pe = {v[2 * e], v[2 * e + 1]};
#if __has_builtin(__builtin_amdgcn_fdot2)
        sB = __builtin_amdgcn_fdot2(pe, pe, sB, false);
#else
        sB += (float)pe[0] * (float)pe[0] + (float)pe[1] * (float)pe[1];
#endif
      }
      *(half8*)(b_dst + ((pass ^ b_swz) << 4)) = v;
    }
    __syncthreads();   // raw consumed before next pass overwrites
  }
  if (tid < TW) As[tid] = sA; else Bs[tid - TW] = sA;
  if (tid < TW + GR - 256) Bs[tid + 256 - TW] = sB;
  __syncthreads();

  // ---- Phase 2: MFMA band + per-pixel soft-argmin ----
  const int lane = tid & 63;
  const int wid  = tid >> 6;
  const int n  = lane & 15;   // fl row within tile (C col)
  const int gq = lane >> 4;   // k-slice / C row group
  const int foffB = n * 64 + ((gq ^ (n & 3)) << 4);
  const float Cbase = (float)(95 - 4 * gq + n);   // kf = Cbase - (16*dq + rg)

  // merged dq0/dq6 selection constants (complementary masks m>=n / m<n)
  const int mmb = gq * 4;
  const bool s0 = (mmb + 0) >= n, s1 = (mmb + 1) >= n;
  const bool s2 = (mmb + 2) >= n, s3 = (mmb + 3) >= n;
  const float kf0 = s0 ? 0.f : 96.f;
  const float kf1 = s1 ? 1.f : 97.f;
  const float kf2 = s2 ? 2.f : 98.f;
  const float kf3 = s3 ? 3.f : 99.f;

  #pragma unroll
  for (int pp = 0; pp < 2; ++pp) {
    const int p = wid * 2 + pp;          // i-tile 0..7
    const half8 bfrag = *(const half8*)((const char*)flH + p * 1024 + foffB);
    f32x4 acc[7];
    #pragma unroll
    for (int dq = 0; dq < 7; ++dq) {
      const half8 afrag = *(const half8*)((const char*)gH + (p + dq) * 1024 + foffB);
      f32x4 z = {0.f, 0.f, 0.f, 0.f};
      acc[dq] = __builtin_amdgcn_mfma_f32_16x16x32_f16(afrag, bfrag, z, 0, 0, 0);
    }

    // pass 1: merged dq0/dq6 cells (all valid, no sentinels) + packed dq1..5
    const float Ai = As[p * 16 + n];
    const f32x4 b40 = *(const f32x4*)(&Bs[p * 16 + mmb]);
    const f32x4 b46 = *(const f32x4*)(&Bs[(p + 6) * 16 + mmb]);
    const float cm0 = fmaf(-2.f, s0 ? acc[0].x : acc[6].x, Ai + (s0 ? b40.x : b46.x));
    const float cm1 = fmaf(-2.f, s1 ? acc[0].y : acc[6].y, Ai + (s1 ? b40.y : b46.y));
    const float cm2 = fmaf(-2.f, s2 ? acc[0].z : acc[6].z, Ai + (s2 ? b40.z : b46.z));
    const float cm3 = fmaf(-2.f, s3 ? acc[0].w : acc[6].w, Ai + (s3 ? b40.w : b46.w));
    float mn = min3f(fminf(cm0, cm1), cm2, cm3);
    float mx = max3f(fmaxf(cm0, cm1), cm2, cm3);

    f32x2 AiP; AiP.x = Ai; AiP.y = Ai;
    f32x2 m2P; m2P.x = -2.f; m2P.y = -2.f;
    #pragma unroll
    for (int dq = 1; dq < 6; ++dq) {
      const f32x4 b4 = *(const f32x4*)(&Bs[(p + dq) * 16 + mmb]);
      const f32x2 c01 = pkfma(m2P, lo2(acc[dq]), pkadd(AiP, lo2(b4)));
      const f32x2 c23 = pkfma(m2P, hi2(acc[dq]), pkadd(AiP, hi2(b4)));
      mn = min3f(mn, c01.x, c01.y);
      mn = min3f(mn, c23.x, c23.y);
      mx = max3f(mx, c01.x, c01.y);
      mx = max3f(mx, c23.x, c23.y);
      acc[dq].x = c01.x; acc[dq].y = c01.y;   // reuse acc as cv storage
      acc[dq].z = c23.x; acc[dq].w = c23.y;
    }
    // cross-lane min/max over the 4 gq lanes: permlane (VALU), no LDS wait
    f32x2 t;
    t = xsw16(mn); mn = fminf(t.x, t.y);
    t = xsw32(mn); mn = fminf(t.x, t.y);
    t = xsw16(mx); mx = fmaxf(t.x, t.y);
    t = xsw32(mx); mx = fmaxf(t.x, t.y);

    // pass 2: w = exp2(na*cv + base); sw = sum(w); skw = sum(kf*w);
    // sdw = Cbase*sw - skw  (kf literal for dq1..5, selected VGPR for merged)
    const float ralpha = 177.0f * 1.4426950408889634f * fastrcp(mx);
    const float na   = -ralpha;
    const float base = ralpha * mn;
    f32x2 naP;   naP.x = na;   naP.y = na;
    f32x2 baseP; baseP.x = base; baseP.y = base;
    const float w0_ = fastexp2(fmaf(na, cm0, base));
    const float w1_ = fastexp2(fmaf(na, cm1, base));
    const float w2_ = fastexp2(fmaf(na, cm2, base));
    const float w3_ = fastexp2(fmaf(na, cm3, base));
    float sw0 = w0_, sw1 = w1_, sw2 = w2_, sw3 = w3_;
    float sk0 = kf0 * w0_;
    float sk1 = kf1 * w1_;
    float sk2 = kf2 * w2_;
    float sk3 = kf3 * w3_;
    #pragma unroll
    for (int dq = 1; dq < 6; ++dq) {
      const f32x2 g01 = pkfma(naP, lo2(acc[dq]), baseP);
      const f32x2 g23 = pkfma(naP, hi2(acc[dq]), baseP);
      const float u0 = fastexp2(g01.x);
      const float u1 = fastexp2(g01.y);
      const float u2 = fastexp2(g23.x);
      const float u3 = fastexp2(g23.y);
      sw0 += u0; sw1 += u1; sw2 += u2; sw3 += u3;
      sk0 = fmaf((float)(16 * dq + 0), u0, sk0);
      sk1 = fmaf((float)(16 * dq + 1), u1, sk1);
      sk2 = fmaf((float)(16 * dq + 2), u2, sk2);
      sk3 = fmaf((float)(16 * dq + 3), u3, sk3);
    }
    float sw  = (sw0 + sw1) + (sw2 + sw3);
    float skw = (sk0 + sk1) + (sk2 + sk3);
    float sdw = fmaf(Cbase, sw, -skw);
    t = xsw16(sw);  sw  = t.x + t.y;
    t = xsw16(sdw); sdw = t.x + t.y;
    t = xsw32(sw);  sw  = t.x + t.y;
    t = xsw32(sdw); sdw = t.x + t.y;
    if (gq == 0)
      out[((size_t)bz * IMG_H + h) * IMG_W + w0 + p * 16 + n] = sdw * fastrcp(sw);
  }
}

extern "C" void kernel_launch(void* const* d_in, const int* in_sizes, int n_in,
                              void* d_out, int out_size, void* d_ws, size_t ws_size,
                              hipStream_t stream) {
  (void)in_sizes; (void)n_in; (void)out_size; (void)ws_size;
  const float* xl   = (const float*)d_in[0];
  const float* xr   = (const float*)d_in[1];
  const float* Wt   = (const float*)d_in[2];
  const float* bias = (const float*)d_in[3];
  _Float16* Fc = (_Float16*)d_ws;   // conv features [4,192,640,32] f16 = 31.5 MB
  float* out = (float*)d_out;       // [2,384,1280] f32

  hipLaunchKernelGGL(conv_relu_kernel, dim3(1920), dim3(256), 0, stream,
                     xl, xr, Wt, bias, Fc);
  hipLaunchKernelGGL(disparity_mfma_kernel, dim3(IMG_W / TW, IMG_H, 2), dim3(256), 0, stream,
                     Fc, out);
}

// Round 13
// 73.600 us; speedup vs baseline: 1.0520x; 1.0520x over previous
//
#include <hip/hip_runtime.h>
#include <cstddef>

typedef _Float16 h2    __attribute__((ext_vector_type(2)));
typedef _Float16 half8 __attribute__((ext_vector_type(8)));
typedef float    f32x4 __attribute__((ext_vector_type(4)));
typedef float    f32x2 __attribute__((ext_vector_type(2)));

#define CH    192
#define CWID  640
#define IMG_H 384
#define IMG_W 1280
#define TW    128
#define GR    224      // g rows staged
#define RAWC  179      // 66 fl cols + 113 g cols (+pad to 192)
#define RAWP  192

__device__ __forceinline__ float fastrcp(float x) {
#if __has_builtin(__builtin_amdgcn_rcpf)
  return __builtin_amdgcn_rcpf(x);
#else
  return 1.0f / x;
#endif
}
__device__ __forceinline__ float fastexp2(float x) {
#if __has_builtin(__builtin_amdgcn_exp2f)
  return __builtin_amdgcn_exp2f(x);
#else
  return exp2f(x);
#endif
}
// Cross-lane pair exchange (xor 16 / xor 32): permlane on gfx950 (pure VALU),
// DS fallbacks otherwise.
__device__ __forceinline__ f32x2 xsw16(float x) {
#if __has_builtin(__builtin_amdgcn_permlane16_swap)
  auto r = __builtin_amdgcn_permlane16_swap(__float_as_uint(x), __float_as_uint(x), false, false);
  f32x2 o; o.x = __uint_as_float(r[0]); o.y = __uint_as_float(r[1]); return o;
#else
  f32x2 o; o.x = x;
  o.y = __uint_as_float((unsigned)__builtin_amdgcn_ds_swizzle((int)__float_as_uint(x), 0x401F));
  return o;
#endif
}
__device__ __forceinline__ f32x2 xsw32(float x) {
#if __has_builtin(__builtin_amdgcn_permlane32_swap)
  auto r = __builtin_amdgcn_permlane32_swap(__float_as_uint(x), __float_as_uint(x), false, false);
  f32x2 o; o.x = __uint_as_float(r[0]); o.y = __uint_as_float(r[1]); return o;
#else
  const int bpa = ((threadIdx.x & 63) ^ 32) << 2;
  f32x2 o; o.x = x;
  o.y = __uint_as_float((unsigned)__builtin_amdgcn_ds_bpermute(bpa, (int)__float_as_uint(x)));
  return o;
#endif
}
// CDNA VOP3P packed-f32 — hipcc never auto-forms these.
__device__ __forceinline__ f32x2 pkadd(f32x2 a, f32x2 b) {
  f32x2 d; asm("v_pk_add_f32 %0, %1, %2" : "=v"(d) : "v"(a), "v"(b)); return d;
}
__device__ __forceinline__ f32x2 pkfma(f32x2 a, f32x2 b, f32x2 c) {
  f32x2 d; asm("v_pk_fma_f32 %0, %1, %2, %3" : "=v"(d) : "v"(a), "v"(b), "v"(c)); return d;
}
__device__ __forceinline__ float min3f(float a, float b, float c) {
  float d; asm("v_min3_f32 %0, %1, %2, %3" : "=v"(d) : "v"(a), "v"(b), "v"(c)); return d;
}
__device__ __forceinline__ float max3f(float a, float b, float c) {
  float d; asm("v_max3_f32 %0, %1, %2, %3" : "=v"(d) : "v"(a), "v"(b), "v"(c)); return d;
}
__device__ __forceinline__ f32x2 lo2(f32x4 v) { f32x2 r; r.x = v.x; r.y = v.y; return r; }
__device__ __forceinline__ f32x2 hi2(f32x4 v) { f32x2 r; r.x = v.z; r.y = v.w; return r; }

// ---------------- Kernel 1: 3x3 stride-2 SAME conv + bias + ReLU -> f16 ----------------
// VERBATIM R4 conv (measured ~18us, no scratch). R6/R7/R8 restructurings all triggered
// allocator scratch demotion of acc[32] (252MB scratch writes). Do not restructure.
__global__ __launch_bounds__(256)
void conv_relu_kernel(const float* __restrict__ xl, const float* __restrict__ xr,
                      const float* __restrict__ Wt, const float* __restrict__ bias,
                      _Float16* __restrict__ Fc) {
  __shared__ float wl[864];
  __shared__ float bl[32];
  const int tid = threadIdx.x;
  for (int t = tid; t < 864; t += 256) wl[t] = Wt[t];
  if (tid < 32) bl[tid] = bias[tid];
  __syncthreads();

  const int g  = blockIdx.x * 256 + tid;   // [0, 4*192*640)
  const int ow = g % CWID;
  const int t2 = g / CWID;
  const int oh = t2 % CH;
  const int bb = t2 / CH;
  const float* src = (bb < 2) ? (xl + (size_t)bb * IMG_H * IMG_W * 3)
                              : (xr + (size_t)(bb - 2) * IMG_H * IMG_W * 3);
  float acc[32];
  #pragma unroll
  for (int c = 0; c < 32; ++c) acc[c] = bl[c];

  #pragma unroll
  for (int kh = 0; kh < 3; ++kh) {
    const int ir = oh * 2 + kh;
    if (ir >= IMG_H) continue;
    #pragma unroll
    for (int kw = 0; kw < 3; ++kw) {
      const int ic = ow * 2 + kw;
      if (ic >= IMG_W) continue;
      const float* px = src + ((size_t)ir * IMG_W + ic) * 3;
      #pragma unroll
      for (int ci = 0; ci < 3; ++ci) {
        const float v = px[ci];
        const float* wp = &wl[((kh * 3 + kw) * 3 + ci) * 32];
        #pragma unroll
        for (int c8 = 0; c8 < 8; ++c8) {
          const float4 w4 = *(const float4*)(wp + c8 * 4);
          acc[c8 * 4 + 0] = fmaf(v, w4.x, acc[c8 * 4 + 0]);
          acc[c8 * 4 + 1] = fmaf(v, w4.y, acc[c8 * 4 + 1]);
          acc[c8 * 4 + 2] = fmaf(v, w4.z, acc[c8 * 4 + 2]);
          acc[c8 * 4 + 3] = fmaf(v, w4.w, acc[c8 * 4 + 3]);
        }
      }
    }
  }
  _Float16 hv[32];
  #pragma unroll
  for (int c = 0; c < 32; ++c) hv[c] = (_Float16)fmaxf(acc[c], 0.f);
  half8* dst = (half8*)(Fc + (size_t)g * 32);
  #pragma unroll
  for (int q = 0; q < 4; ++q) {
    half8 o;
    #pragma unroll
    for (int e = 0; e < 8; ++e) o[e] = hv[q * 8 + e];
    dst[q] = o;
  }
}

// ------- Kernel 2: f16 MFMA cost volume + soft-argmin -------
// Tile slot swizzle uses row bits 1-2 ((r>>1)&3): bank-quad = 4*(n&1) + slot covers
// all 8 quads across 8 consecutive lanes -> conflict-free tile writes & frag reads
// (old (r&3) swizzle collided n with n+4: 2-way conflict on every tile access).
__global__ __launch_bounds__(256, 4)
void disparity_mfma_kernel(const _Float16* __restrict__ Fc, float* __restrict__ out) {
  __shared__ alignas(16) _Float16 raw[RAWP * 16];   // 6 KB: 192 rows x 32B (2 chunks)
  __shared__ alignas(16) _Float16 flH[8 * 512];     // 8 tiles [16][32] f16
  __shared__ alignas(16) _Float16 gH[14 * 512];     // 14 tiles
  __shared__ alignas(16) float As[TW];
  __shared__ alignas(16) float Bs[GR];

  const int tid = threadIdx.x;
  const int w0  = blockIdx.x * TW;
  const int h   = blockIdx.y;
  const int bz  = blockIdx.z;

  // vertical bilinear params (half-pixel, clamped)
  const int hk = h >> 1;
  int r0, r1; float wv0;
  if (h & 1) { r0 = hk; r1 = (hk + 1 > CH - 1) ? CH - 1 : hk + 1; wv0 = 0.75f; }
  else       { r0 = (hk - 1 < 0) ? 0 : hk - 1; r1 = hk;           wv0 = 0.25f; }
  const half8 w0v = (half8)(_Float16)wv0;
  const half8 w1v = (half8)(_Float16)(1.0f - wv0);

  const int vbaseL = (w0 >> 1) + 639;  // fl raw region (t 0..65)
  const int vbaseR = (w0 >> 1) + 592;  // g raw region (t 66..178)

  char* const rawB = (char*)raw;

  // scalar row bases (hoisted 64-bit math)
  const char* const bL0 = (const char*)(Fc + ((size_t)bz * CH + r0) * CWID * 32);
  const char* const bL1 = (const char*)(Fc + ((size_t)bz * CH + r1) * CWID * 32);
  const char* const bR0 = (const char*)(Fc + ((size_t)(bz + 2) * CH + r0) * CWID * 32);
  const char* const bR1 = (const char*)(Fc + ((size_t)(bz + 2) * CH + r1) * CWID * 32);

  // ---- precompute phase-1 row params for row A = tid and row B = tid+256 ----
  const _Float16 h75 = (_Float16)0.75f, h25 = (_Float16)0.25f;
  int a_r0off, a_s0, a_r1off, a_s1, a_swz; half8 a_h0, a_h1; char* a_dst;
  int b_r0off, b_s0, b_r1off, b_s1, b_swz; half8 b_h0, b_h1; char* b_dst;
  {
    const int row = tid;
    const bool isfl = row < TW;
    const int r  = isfl ? row : row - TW;
    const int uv = isfl ? (w0 + r) : (w0 - 95 + r);
    const int uact = uv < 0 ? uv + IMG_W : (uv >= IMG_W ? uv - IMG_W : uv);
    const int up = uv + IMG_W;
    const int vm0 = (up - 1) >> 1;
    int t0 = vm0 - (isfl ? vbaseL : (vbaseR - 66));
    int t1 = t0 + 1;
    if (uact == 0)         t0 = t1;
    if (uact == IMG_W - 1) t1 = t0;
    a_h0 = (half8)((up & 1) ? h75 : h25);
    a_h1 = (half8)((up & 1) ? h25 : h75);
    a_r0off = t0 * 32; a_s0 = (t0 & 1) << 4;
    a_r1off = t1 * 32; a_s1 = (t1 & 1) << 4;
    a_swz = (r >> 1) & 3;
    a_dst = (char*)(isfl ? flH : gH) + (r >> 4) * 1024 + (r & 15) * 64;
  }
  {
    const int row = tid + 256;   // always a g row (256..351) when used
    const int r  = row - TW;
    const int uv = w0 - 95 + r;
    const int uact = uv < 0 ? uv + IMG_W : (uv >= IMG_W ? uv - IMG_W : uv);
    const int up = uv + IMG_W;
    const int vm0 = (up - 1) >> 1;
    int t0 = vm0 - (vbaseR - 66);
    int t1 = t0 + 1;
    if (uact == 0)         t0 = t1;
    if (uact == IMG_W - 1) t1 = t0;
    b_h0 = (half8)((up & 1) ? h75 : h25);
    b_h1 = (half8)((up & 1) ? h25 : h75);
    b_r0off = t0 * 32; b_s0 = (t0 & 1) << 4;
    b_r1off = t1 * 32; b_s1 = (t1 & 1) << 4;
    b_swz = (r >> 1) & 3;
    b_dst = (char*)gH + (r >> 4) * 1024 + (r & 15) * 64;
  }

  float sA = 0.f, sB = 0.f;
  #pragma unroll
  for (int half = 0; half < 2; ++half) {
    // ---- Phase 0: stage 2 channel-chunks of this half + vertical blend ----
    #pragma unroll
    for (int it = 0; it < 2; ++it) {
      const int task = tid + it * 256;     // 384 tasks (192 t x 2 cpos)
      if (it == 0 || tid < 128) {
        const int t    = task >> 1;
        const int cpos = task & 1;
        const int tc   = (t > RAWC - 1) ? RAWC - 1 : t;
        const bool isfl = tc < 66;
        int v = isfl ? (vbaseL + tc) : (vbaseR + tc - 66);   // in [592, 1280]
        v -= (v >= 640) ? 640 : 0;
        v -= (v >= 640) ? 640 : 0;                            // 1280 -> 0 (roll wrap)
        const char* p0 = isfl ? bL0 : bR0;
        const char* p1 = isfl ? bL1 : bR1;
        const int off = (v << 6) + ((half * 2 + cpos) << 4);
        const half8 a0 = *(const half8*)(p0 + off);
        const half8 a1 = *(const half8*)(p1 + off);
        const half8 vv = a0 * w0v + a1 * w1v;
        *(half8*)(rawB + t * 32 + ((cpos ^ (t & 1)) << 4)) = vv;
      }
    }
    __syncthreads();

    // ---- Phase 1: horizontal blend + tiles + norm partials (this half) ----
    #pragma unroll
    for (int cpos = 0; cpos < 2; ++cpos) {
      const int c16 = half * 2 + cpos;
      const int cb  = cpos << 4;
      {
        const half8 a = *(const half8*)(rawB + a_r0off + (cb ^ a_s0));
        const half8 b = *(const half8*)(rawB + a_r1off + (cb ^ a_s1));
        const half8 v = a * a_h0 + b * a_h1;
        #pragma unroll
        for (int e = 0; e < 4; ++e) {
          h2 pe = {v[2 * e], v[2 * e + 1]};
#if __has_builtin(__builtin_amdgcn_fdot2)
          sA = __builtin_amdgcn_fdot2(pe, pe, sA, false);
#else
          sA += (float)pe[0] * (float)pe[0] + (float)pe[1] * (float)pe[1];
#endif
        }
        *(half8*)(a_dst + ((c16 ^ a_swz) << 4)) = v;
      }
      if (tid < TW + GR - 256) {
        const half8 a = *(const half8*)(rawB + b_r0off + (cb ^ b_s0));
        const half8 b = *(const half8*)(rawB + b_r1off + (cb ^ b_s1));
        const half8 v = a * b_h0 + b * b_h1;
        #pragma unroll
        for (int e = 0; e < 4; ++e) {
          h2 pe = {v[2 * e], v[2 * e + 1]};
#if __has_builtin(__builtin_amdgcn_fdot2)
          sB = __builtin_amdgcn_fdot2(pe, pe, sB, false);
#else
          sB += (float)pe[0] * (float)pe[0] + (float)pe[1] * (float)pe[1];
#endif
        }
        *(half8*)(b_dst + ((c16 ^ b_swz) << 4)) = v;
      }
    }
    __syncthreads();   // raw reads done before next half overwrites
  }
  if (tid < TW) As[tid] = sA; else Bs[tid - TW] = sA;
  if (tid < TW + GR - 256) Bs[tid + 256 - TW] = sB;
  __syncthreads();

  // ---- Phase 2: MFMA band + per-pixel soft-argmin ----
  const int lane = tid & 63;
  const int wid  = tid >> 6;
  const int n  = lane & 15;   // fl row within tile (C col)
  const int gq = lane >> 4;   // k-slice / C row group
  const int foffB = n * 64 + ((gq ^ ((n >> 1) & 3)) << 4);
  const float Cbase = (float)(95 - 4 * gq + n);   // kf = Cbase - (16*dq + rg)

  // merged dq0/dq6 selection constants (complementary masks m>=n / m<n)
  const int mmb = gq * 4;
  const bool s0 = (mmb + 0) >= n, s1 = (mmb + 1) >= n;
  const bool s2 = (mmb + 2) >= n, s3 = (mmb + 3) >= n;
  const float kf0 = s0 ? 0.f : 96.f;
  const float kf1 = s1 ? 1.f : 97.f;
  const float kf2 = s2 ? 2.f : 98.f;
  const float kf3 = s3 ? 3.f : 99.f;

  #pragma unroll
  for (int pp = 0; pp < 2; ++pp) {
    const int p = wid * 2 + pp;          // i-tile 0..7
    const half8 bfrag = *(const half8*)((const char*)flH + p * 1024 + foffB);
    f32x4 acc[7];
    #pragma unroll
    for (int dq = 0; dq < 7; ++dq) {
      const half8 afrag = *(const half8*)((const char*)gH + (p + dq) * 1024 + foffB);
      f32x4 z = {0.f, 0.f, 0.f, 0.f};
      acc[dq] = __builtin_amdgcn_mfma_f32_16x16x32_f16(afrag, bfrag, z, 0, 0, 0);
    }

    // pass 1: merged dq0/dq6 cells (all valid, no sentinels) + packed dq1..5
    const float Ai = As[p * 16 + n];
    const f32x4 b40 = *(const f32x4*)(&Bs[p * 16 + mmb]);
    const f32x4 b46 = *(const f32x4*)(&Bs[(p + 6) * 16 + mmb]);
    const float cm0 = fmaf(-2.f, s0 ? acc[0].x : acc[6].x, Ai + (s0 ? b40.x : b46.x));
    const float cm1 = fmaf(-2.f, s1 ? acc[0].y : acc[6].y, Ai + (s1 ? b40.y : b46.y));
    const float cm2 = fmaf(-2.f, s2 ? acc[0].z : acc[6].z, Ai + (s2 ? b40.z : b46.z));
    const float cm3 = fmaf(-2.f, s3 ? acc[0].w : acc[6].w, Ai + (s3 ? b40.w : b46.w));
    float mn = min3f(fminf(cm0, cm1), cm2, cm3);
    float mx = max3f(fmaxf(cm0, cm1), cm2, cm3);

    f32x2 AiP; AiP.x = Ai; AiP.y = Ai;
    f32x2 m2P; m2P.x = -2.f; m2P.y = -2.f;
    #pragma unroll
    for (int dq = 1; dq < 6; ++dq) {
      const f32x4 b4 = *(const f32x4*)(&Bs[(p + dq) * 16 + mmb]);
      const f32x2 c01 = pkfma(m2P, lo2(acc[dq]), pkadd(AiP, lo2(b4)));
      const f32x2 c23 = pkfma(m2P, hi2(acc[dq]), pkadd(AiP, hi2(b4)));
      mn = min3f(mn, c01.x, c01.y);
      mn = min3f(mn, c23.x, c23.y);
      mx = max3f(mx, c01.x, c01.y);
      mx = max3f(mx, c23.x, c23.y);
      acc[dq].x = c01.x; acc[dq].y = c01.y;   // reuse acc as cv storage
      acc[dq].z = c23.x; acc[dq].w = c23.y;
    }
    // cross-lane min/max over the 4 gq lanes: permlane (VALU), no LDS wait
    f32x2 t;
    t = xsw16(mn); mn = fminf(t.x, t.y);
    t = xsw32(mn); mn = fminf(t.x, t.y);
    t = xsw16(mx); mx = fmaxf(t.x, t.y);
    t = xsw32(mx); mx = fmaxf(t.x, t.y);

    // pass 2: w = exp2(na*cv + base); sw = sum(w); skw = sum(kf*w);
    // sdw = Cbase*sw - skw  (kf literal for dq1..5, selected VGPR for merged)
    const float ralpha = 177.0f * 1.4426950408889634f * fastrcp(mx);
    const float na   = -ralpha;
    const float base = ralpha * mn;
    f32x2 naP;   naP.x = na;   naP.y = na;
    f32x2 baseP; baseP.x = base; baseP.y = base;
    const float w0_ = fastexp2(fmaf(na, cm0, base));
    const float w1_ = fastexp2(fmaf(na, cm1, base));
    const float w2_ = fastexp2(fmaf(na, cm2, base));
    const float w3_ = fastexp2(fmaf(na, cm3, base));
    float sw0 = w0_, sw1 = w1_, sw2 = w2_, sw3 = w3_;
    float sk0 = kf0 * w0_;
    float sk1 = kf1 * w1_;
    float sk2 = kf2 * w2_;
    float sk3 = kf3 * w3_;
    #pragma unroll
    for (int dq = 1; dq < 6; ++dq) {
      const f32x2 g01 = pkfma(naP, lo2(acc[dq]), baseP);
      const f32x2 g23 = pkfma(naP, hi2(acc[dq]), baseP);
      const float u0 = fastexp2(g01.x);
      const float u1 = fastexp2(g01.y);
      const float u2 = fastexp2(g23.x);
      const float u3 = fastexp2(g23.y);
      sw0 += u0; sw1 += u1; sw2 += u2; sw3 += u3;
      sk0 = fmaf((float)(16 * dq + 0), u0, sk0);
      sk1 = fmaf((float)(16 * dq + 1), u1, sk1);
      sk2 = fmaf((float)(16 * dq + 2), u2, sk2);
      sk3 = fmaf((float)(16 * dq + 3), u3, sk3);
    }
    float sw  = (sw0 + sw1) + (sw2 + sw3);
    float skw = (sk0 + sk1) + (sk2 + sk3);
    float sdw = fmaf(Cbase, sw, -skw);
    t = xsw16(sw);  sw  = t.x + t.y;
    t = xsw16(sdw); sdw = t.x + t.y;
    t = xsw32(sw);  sw  = t.x + t.y;
    t = xsw32(sdw); sdw = t.x + t.y;
    if (gq == 0)
      out[((size_t)bz * IMG_H + h) * IMG_W + w0 + p * 16 + n] = sdw * fastrcp(sw);
  }
}

extern "C" void kernel_launch(void* const* d_in, const int* in_sizes, int n_in,
                              void* d_out, int out_size, void* d_ws, size_t ws_size,
                              hipStream_t stream) {
  (void)in_sizes; (void)n_in; (void)out_size; (void)ws_size;
  const float* xl   = (const float*)d_in[0];
  const float* xr   = (const float*)d_in[1];
  const float* Wt   = (const float*)d_in[2];
  const float* bias = (const float*)d_in[3];
  _Float16* Fc = (_Float16*)d_ws;   // conv features [4,192,640,32] f16 = 31.5 MB
  float* out = (float*)d_out;       // [2,384,1280] f32

  hipLaunchKernelGGL(conv_relu_kernel, dim3(1920), dim3(256), 0, stream,
                     xl, xr, Wt, bias, Fc);
  hipLaunchKernelGGL(disparity_mfma_kernel, dim3(IMG_W / TW, IMG_H, 2), dim3(256), 0, stream,
                     Fc, out);
}

// Round 14
// 71.335 us; speedup vs baseline: 1.0854x; 1.0318x over previous
//
#include <hip/hip_runtime.h>
#include <cstddef>

typedef _Float16 h2    __attribute__((ext_vector_type(2)));
typedef _Float16 half4 __attribute__((ext_vector_type(4)));
typedef _Float16 half8 __attribute__((ext_vector_type(8)));
typedef float    f32x4 __attribute__((ext_vector_type(4)));
typedef float    f32x2 __attribute__((ext_vector_type(2)));

#define CH    192
#define CWID  640
#define IMG_H 384
#define IMG_W 1280
#define TW    128
#define GR    224      // g rows staged
#define RAWC  179      // 66 fl cols + 113 g cols
#define RAWP  192

__device__ __forceinline__ float fastrcp(float x) {
#if __has_builtin(__builtin_amdgcn_rcpf)
  return __builtin_amdgcn_rcpf(x);
#else
  return 1.0f / x;
#endif
}
__device__ __forceinline__ float fastexp2(float x) {
#if __has_builtin(__builtin_amdgcn_exp2f)
  return __builtin_amdgcn_exp2f(x);
#else
  return exp2f(x);
#endif
}
__device__ __forceinline__ f32x2 xsw16(float x) {
#if __has_builtin(__builtin_amdgcn_permlane16_swap)
  auto r = __builtin_amdgcn_permlane16_swap(__float_as_uint(x), __float_as_uint(x), false, false);
  f32x2 o; o.x = __uint_as_float(r[0]); o.y = __uint_as_float(r[1]); return o;
#else
  f32x2 o; o.x = x;
  o.y = __uint_as_float((unsigned)__builtin_amdgcn_ds_swizzle((int)__float_as_uint(x), 0x401F));
  return o;
#endif
}
__device__ __forceinline__ f32x2 xsw32(float x) {
#if __has_builtin(__builtin_amdgcn_permlane32_swap)
  auto r = __builtin_amdgcn_permlane32_swap(__float_as_uint(x), __float_as_uint(x), false, false);
  f32x2 o; o.x = __uint_as_float(r[0]); o.y = __uint_as_float(r[1]); return o;
#else
  const int bpa = ((threadIdx.x & 63) ^ 32) << 2;
  f32x2 o; o.x = x;
  o.y = __uint_as_float((unsigned)__builtin_amdgcn_ds_bpermute(bpa, (int)__float_as_uint(x)));
  return o;
#endif
}
__device__ __forceinline__ f32x2 pkfma(f32x2 a, f32x2 b, f32x2 c) {
  f32x2 d; asm("v_pk_fma_f32 %0, %1, %2, %3" : "=v"(d) : "v"(a), "v"(b), "v"(c)); return d;
}
__device__ __forceinline__ float min3f(float a, float b, float c) {
  float d; asm("v_min3_f32 %0, %1, %2, %3" : "=v"(d) : "v"(a), "v"(b), "v"(c)); return d;
}
__device__ __forceinline__ float max3f(float a, float b, float c) {
  float d; asm("v_max3_f32 %0, %1, %2, %3" : "=v"(d) : "v"(a), "v"(b), "v"(c)); return d;
}
__device__ __forceinline__ f32x2 lo2(f32x4 v) { f32x2 r; r.x = v.x; r.y = v.y; return r; }
__device__ __forceinline__ f32x2 hi2(f32x4 v) { f32x2 r; r.x = v.z; r.y = v.w; return r; }

// ---------------- Kernel 1: conv as MFMA im2col GEMM ----------------
// [256 px/block] x [32 ch], K=27 pad 32. f16 hi/lo split (h=RNE(v), l=v-h):
// error ~2^-22 rel == effectively f32, so features match the old f32 conv to
// well below the f16 storage quantum. Revert path: R9 scalar conv.
__global__ __launch_bounds__(256)
void conv_mfma_kernel(const float* __restrict__ xl, const float* __restrict__ xr,
                      const float* __restrict__ Wt, const float* __restrict__ bias,
                      _Float16* __restrict__ Fc) {
  __shared__ alignas(16) float lin[5 * 776];        // 15.5 KB input tile f32
  __shared__ alignas(16) _Float16 Ph[256 * 32];     // 16 KB im2col hi
  __shared__ alignas(16) _Float16 Pl[256 * 32];     // 16 KB im2col lo
  __shared__ alignas(16) _Float16 Wh[32 * 32];      // 2 KB  W hi [ch][K]
  __shared__ alignas(16) _Float16 Wl[32 * 32];      // 2 KB  W lo
  __shared__ float bl[32];

  const int tid = threadIdx.x;
  const int bx = blockIdx.x;        // 0..4  (128-ow tiles)
  const int by = blockIdx.y;        // 0..95 (oh pairs)
  const int bb = blockIdx.z;        // 0..3
  const float* src = (bb < 2) ? (xl + (size_t)bb * (IMG_H * IMG_W * 3))
                              : (xr + (size_t)(bb - 2) * (IMG_H * IMG_W * 3));

  // ---- stage 5 input rows x 774 floats (258 cols x 3ch), coalesced, zero-pad ----
  const int fbase = bx * 768;
  #pragma unroll
  for (int r = 0; r < 5; ++r) {
    const int ir = by * 4 + r;
    const float* grow = src + (size_t)ir * 3840;
    #pragma unroll
    for (int j = 0; j < 2; ++j) {
      const int pr = tid + j * 256;
      if (pr < 388) {
        const int fo = fbase + 2 * pr;
        float2 v; v.x = 0.f; v.y = 0.f;
        if (ir < IMG_H && fo < 3840) v = *(const float2*)(grow + fo);  // fo even -> full pair in-range
        *(float2*)(&lin[r * 776 + 2 * pr]) = v;
      }
    }
  }
  // ---- stage W transposed to [ch][K=32] with f16 hi/lo split ----
  if (tid < 128) {
    const int ch = tid >> 2, ck = tid & 3;
    half8 hv, lv;
    #pragma unroll
    for (int e = 0; e < 8; ++e) {
      const int k = ck * 8 + e;
      const float v = (k < 27) ? Wt[k * 32 + ch] : 0.f;
      const _Float16 hh = (_Float16)v;
      hv[e] = hh;
      lv[e] = (_Float16)(v - (float)hh);
    }
    const int off = ch * 32 + ((ck ^ ((ch >> 1) & 3)) << 3);
    *(half8*)(&Wh[off]) = hv;
    *(half8*)(&Wl[off]) = lv;
  }
  if (tid < 32) bl[tid] = bias[tid];
  __syncthreads();

  // ---- im2col: thread owns px=tid. K-order (kh,kw,ci) = 3 runs of 9 contiguous
  // floats starting at lin[row 2*doh+kh][6*dow]. Chunk c holds k=8c..8c+7. ----
  {
    const int dow = tid & 127;
    const int doh = tid >> 7;
    const int pb = tid * 32;
    const int sz = (tid >> 1) & 3;
    auto emit = [&](int c, float v0, float v1, float v2, float v3,
                    float v4, float v5, float v6, float v7) {
      const float vv[8] = {v0, v1, v2, v3, v4, v5, v6, v7};
      half8 hv, lv;
      #pragma unroll
      for (int e = 0; e < 8; ++e) {
        const _Float16 hh = (_Float16)vv[e];
        hv[e] = hh;
        lv[e] = (_Float16)(vv[e] - (float)hh);
      }
      const int off = pb + ((c ^ sz) << 3);
      *(half8*)(&Ph[off]) = hv;
      *(half8*)(&Pl[off]) = lv;
    };
    const int lb0 = (doh * 2) * 776 + 6 * dow;
    const float2 a0 = *(const float2*)(&lin[lb0 + 0]);
    const float2 a1 = *(const float2*)(&lin[lb0 + 2]);
    const float2 a2 = *(const float2*)(&lin[lb0 + 4]);
    const float2 a3 = *(const float2*)(&lin[lb0 + 6]);
    const float  a8 = lin[lb0 + 8];
    emit(0, a0.x, a0.y, a1.x, a1.y, a2.x, a2.y, a3.x, a3.y);
    const int lb1 = lb0 + 776;
    const float2 b0 = *(const float2*)(&lin[lb1 + 0]);
    const float2 b1 = *(const float2*)(&lin[lb1 + 2]);
    const float2 b2 = *(const float2*)(&lin[lb1 + 4]);
    const float2 b3 = *(const float2*)(&lin[lb1 + 6]);
    const float  b8 = lin[lb1 + 8];
    emit(1, a8, b0.x, b0.y, b1.x, b1.y, b2.x, b2.y, b3.x);
    const int lb2 = lb0 + 1552;
    const float2 d0 = *(const float2*)(&lin[lb2 + 0]);
    const float2 d1 = *(const float2*)(&lin[lb2 + 2]);
    const float2 d2 = *(const float2*)(&lin[lb2 + 4]);
    const float2 d3 = *(const float2*)(&lin[lb2 + 6]);
    const float  d8 = lin[lb2 + 8];
    emit(2, b3.y, b8, d0.x, d0.y, d1.x, d1.y, d2.x, d2.y);
    emit(3, d3.x, d3.y, d8, 0.f, 0.f, 0.f, 0.f, 0.f);
  }
  __syncthreads();

  // ---- MFMA: D[m=ch][n=px]; 4 px-tiles x 2 ch-tiles x 3 split-MFMAs per wave ----
  const int lane = tid & 63, wv = tid >> 6;
  const int n  = lane & 15;
  const int gq = lane >> 4;
  const int fs = (gq ^ ((n >> 1) & 3)) << 3;     // ((16+n)>>1)&3 == (n>>1)&3
  const half8 wh0 = *(const half8*)(&Wh[n * 32 + fs]);
  const half8 wl0 = *(const half8*)(&Wl[n * 32 + fs]);
  const half8 wh1 = *(const half8*)(&Wh[(16 + n) * 32 + fs]);
  const half8 wl1 = *(const half8*)(&Wl[(16 + n) * 32 + fs]);
  const float bb0 = bl[gq * 4 + 0], bb1 = bl[gq * 4 + 1];
  const float bb2 = bl[gq * 4 + 2], bb3 = bl[gq * 4 + 3];
  const float bc0 = bl[16 + gq * 4 + 0], bc1 = bl[16 + gq * 4 + 1];
  const float bc2 = bl[16 + gq * 4 + 2], bc3 = bl[16 + gq * 4 + 3];

  #pragma unroll
  for (int t = 0; t < 4; ++t) {
    const int px = wv * 64 + t * 16 + n;
    const int poff = px * 32 + fs;                // (px>>1)&3 == (n>>1)&3
    const half8 ph = *(const half8*)(&Ph[poff]);
    const half8 pl = *(const half8*)(&Pl[poff]);
    f32x4 z0 = {0.f, 0.f, 0.f, 0.f};
    z0 = __builtin_amdgcn_mfma_f32_16x16x32_f16(wh0, pl, z0, 0, 0, 0);
    z0 = __builtin_amdgcn_mfma_f32_16x16x32_f16(wl0, ph, z0, 0, 0, 0);
    z0 = __builtin_amdgcn_mfma_f32_16x16x32_f16(wh0, ph, z0, 0, 0, 0);
    f32x4 z1 = {0.f, 0.f, 0.f, 0.f};
    z1 = __builtin_amdgcn_mfma_f32_16x16x32_f16(wh1, pl, z1, 0, 0, 0);
    z1 = __builtin_amdgcn_mfma_f32_16x16x32_f16(wl1, ph, z1, 0, 0, 0);
    z1 = __builtin_amdgcn_mfma_f32_16x16x32_f16(wh1, ph, z1, 0, 0, 0);

    const int ow = bx * 128 + (px & 127);
    const int oh = by * 2 + (px >> 7);
    _Float16* fp = Fc + ((size_t)(bb * CH + oh) * CWID + ow) * 32 + gq * 4;
    half4 o0, o1;
    o0[0] = (_Float16)fmaxf(z0[0] + bb0, 0.f);
    o0[1] = (_Float16)fmaxf(z0[1] + bb1, 0.f);
    o0[2] = (_Float16)fmaxf(z0[2] + bb2, 0.f);
    o0[3] = (_Float16)fmaxf(z0[3] + bb3, 0.f);
    o1[0] = (_Float16)fmaxf(z1[0] + bc0, 0.f);
    o1[1] = (_Float16)fmaxf(z1[1] + bc1, 0.f);
    o1[2] = (_Float16)fmaxf(z1[2] + bc2, 0.f);
    o1[3] = (_Float16)fmaxf(z1[3] + bc3, 0.f);
    *(half4*)(fp)      = o0;
    *(half4*)(fp + 16) = o1;
  }
}

// ------- Kernel 2: f16 MFMA cost volume + soft-argmin -------
// Softmax is shift-invariant in cost: per-cell math uses u = B - 2*corr (Ai
// dropped from all 28 cells); Ai enters once via ralpha = c/(Ai + max u).
__global__ __launch_bounds__(256, 4)
void disparity_mfma_kernel(const _Float16* __restrict__ Fc, float* __restrict__ out) {
  __shared__ alignas(16) _Float16 raw[RAWP * 16];
  __shared__ alignas(16) _Float16 flH[8 * 512];
  __shared__ alignas(16) _Float16 gH[14 * 512];
  __shared__ alignas(16) float As[TW];
  __shared__ alignas(16) float Bs[GR];

  const int tid = threadIdx.x;
  const int w0  = blockIdx.x * TW;
  const int h   = blockIdx.y;
  const int bz  = blockIdx.z;

  const int hk = h >> 1;
  int r0, r1; float wv0;
  if (h & 1) { r0 = hk; r1 = (hk + 1 > CH - 1) ? CH - 1 : hk + 1; wv0 = 0.75f; }
  else       { r0 = (hk - 1 < 0) ? 0 : hk - 1; r1 = hk;           wv0 = 0.25f; }
  const half8 w0v = (half8)(_Float16)wv0;
  const half8 w1v = (half8)(_Float16)(1.0f - wv0);

  const int vbaseL = (w0 >> 1) + 639;
  const int vbaseR = (w0 >> 1) + 592;

  char* const rawB = (char*)raw;

  const char* const bL0 = (const char*)(Fc + ((size_t)bz * CH + r0) * CWID * 32);
  const char* const bL1 = (const char*)(Fc + ((size_t)bz * CH + r1) * CWID * 32);
  const char* const bR0 = (const char*)(Fc + ((size_t)(bz + 2) * CH + r0) * CWID * 32);
  const char* const bR1 = (const char*)(Fc + ((size_t)(bz + 2) * CH + r1) * CWID * 32);

  const _Float16 h75 = (_Float16)0.75f, h25 = (_Float16)0.25f;
  int a_r0off, a_s0, a_r1off, a_s1, a_swz; half8 a_h0, a_h1; char* a_dst;
  int b_r0off, b_s0, b_r1off, b_s1, b_swz; half8 b_h0, b_h1; char* b_dst;
  {
    const int row = tid;
    const bool isfl = row < TW;
    const int r  = isfl ? row : row - TW;
    const int uv = isfl ? (w0 + r) : (w0 - 95 + r);
    const int uact = uv < 0 ? uv + IMG_W : (uv >= IMG_W ? uv - IMG_W : uv);
    const int up = uv + IMG_W;
    const int vm0 = (up - 1) >> 1;
    int t0 = vm0 - (isfl ? vbaseL : (vbaseR - 66));
    int t1 = t0 + 1;
    if (uact == 0)         t0 = t1;
    if (uact == IMG_W - 1) t1 = t0;
    a_h0 = (half8)((up & 1) ? h75 : h25);
    a_h1 = (half8)((up & 1) ? h25 : h75);
    a_r0off = t0 * 32; a_s0 = (t0 & 1) << 4;
    a_r1off = t1 * 32; a_s1 = (t1 & 1) << 4;
    a_swz = (r >> 1) & 3;
    a_dst = (char*)(isfl ? flH : gH) + (r >> 4) * 1024 + (r & 15) * 64;
  }
  {
    const int row = tid + 256;
    const int r  = row - TW;
    const int uv = w0 - 95 + r;
    const int uact = uv < 0 ? uv + IMG_W : (uv >= IMG_W ? uv - IMG_W : uv);
    const int up = uv + IMG_W;
    const int vm0 = (up - 1) >> 1;
    int t0 = vm0 - (vbaseR - 66);
    int t1 = t0 + 1;
    if (uact == 0)         t0 = t1;
    if (uact == IMG_W - 1) t1 = t0;
    b_h0 = (half8)((up & 1) ? h75 : h25);
    b_h1 = (half8)((up & 1) ? h25 : h75);
    b_r0off = t0 * 32; b_s0 = (t0 & 1) << 4;
    b_r1off = t1 * 32; b_s1 = (t1 & 1) << 4;
    b_swz = (r >> 1) & 3;
    b_dst = (char*)gH + (r >> 4) * 1024 + (r & 15) * 64;
  }

  float sA = 0.f, sB = 0.f;
  #pragma unroll
  for (int half = 0; half < 2; ++half) {
    #pragma unroll
    for (int it = 0; it < 2; ++it) {
      const int task = tid + it * 256;
      if (it == 0 || tid < 128) {
        const int t    = task >> 1;
        const int cpos = task & 1;
        const int tc   = (t > RAWC - 1) ? RAWC - 1 : t;
        const bool isfl = tc < 66;
        int v = isfl ? (vbaseL + tc) : (vbaseR + tc - 66);
        v -= (v >= 640) ? 640 : 0;
        v -= (v >= 640) ? 640 : 0;
        const char* p0 = isfl ? bL0 : bR0;
        const char* p1 = isfl ? bL1 : bR1;
        const int off = (v << 6) + ((half * 2 + cpos) << 4);
        const half8 a0 = *(const half8*)(p0 + off);
        const half8 a1 = *(const half8*)(p1 + off);
        const half8 vv = a0 * w0v + a1 * w1v;
        *(half8*)(rawB + t * 32 + ((cpos ^ (t & 1)) << 4)) = vv;
      }
    }
    __syncthreads();

    #pragma unroll
    for (int cpos = 0; cpos < 2; ++cpos) {
      const int c16 = half * 2 + cpos;
      const int cb  = cpos << 4;
      {
        const half8 a = *(const half8*)(rawB + a_r0off + (cb ^ a_s0));
        const half8 b = *(const half8*)(rawB + a_r1off + (cb ^ a_s1));
        const half8 v = a * a_h0 + b * a_h1;
        #pragma unroll
        for (int e = 0; e < 4; ++e) {
          h2 pe = {v[2 * e], v[2 * e + 1]};
#if __has_builtin(__builtin_amdgcn_fdot2)
          sA = __builtin_amdgcn_fdot2(pe, pe, sA, false);
#else
          sA += (float)pe[0] * (float)pe[0] + (float)pe[1] * (float)pe[1];
#endif
        }
        *(half8*)(a_dst + ((c16 ^ a_swz) << 4)) = v;
      }
      if (tid < TW + GR - 256) {
        const half8 a = *(const half8*)(rawB + b_r0off + (cb ^ b_s0));
        const half8 b = *(const half8*)(rawB + b_r1off + (cb ^ b_s1));
        const half8 v = a * b_h0 + b * b_h1;
        #pragma unroll
        for (int e = 0; e < 4; ++e) {
          h2 pe = {v[2 * e], v[2 * e + 1]};
#if __has_builtin(__builtin_amdgcn_fdot2)
          sB = __builtin_amdgcn_fdot2(pe, pe, sB, false);
#else
          sB += (float)pe[0] * (float)pe[0] + (float)pe[1] * (float)pe[1];
#endif
        }
        *(half8*)(b_dst + ((c16 ^ b_swz) << 4)) = v;
      }
    }
    __syncthreads();
  }
  if (tid < TW) As[tid] = sA; else Bs[tid - TW] = sA;
  if (tid < TW + GR - 256) Bs[tid + 256 - TW] = sB;
  __syncthreads();

  const int lane = tid & 63;
  const int wid  = tid >> 6;
  const int n  = lane & 15;
  const int gq = lane >> 4;
  const int foffB = n * 64 + ((gq ^ ((n >> 1) & 3)) << 4);
  const float Cbase = (float)(95 - 4 * gq + n);

  const int mmb = gq * 4;
  const bool s0 = (mmb + 0) >= n, s1 = (mmb + 1) >= n;
  const bool s2 = (mmb + 2) >= n, s3 = (mmb + 3) >= n;
  const float kf0 = s0 ? 0.f : 96.f;
  const float kf1 = s1 ? 1.f : 97.f;
  const float kf2 = s2 ? 2.f : 98.f;
  const float kf3 = s3 ? 3.f : 99.f;

  #pragma unroll
  for (int pp = 0; pp < 2; ++pp) {
    const int p = wid * 2 + pp;
    const half8 bfrag = *(const half8*)((const char*)flH + p * 1024 + foffB);
    f32x4 acc[7];
    #pragma unroll
    for (int dq = 0; dq < 7; ++dq) {
      const half8 afrag = *(const half8*)((const char*)gH + (p + dq) * 1024 + foffB);
      f32x4 z = {0.f, 0.f, 0.f, 0.f};
      acc[dq] = __builtin_amdgcn_mfma_f32_16x16x32_f16(afrag, bfrag, z, 0, 0, 0);
    }

    // pass 1 in u-space (u = B - 2*corr; Ai dropped by shift invariance)
    const float Ai = As[p * 16 + n];
    const f32x4 b40 = *(const f32x4*)(&Bs[p * 16 + mmb]);
    const f32x4 b46 = *(const f32x4*)(&Bs[(p + 6) * 16 + mmb]);
    const float cm0 = fmaf(-2.f, s0 ? acc[0].x : acc[6].x, s0 ? b40.x : b46.x);
    const float cm1 = fmaf(-2.f, s1 ? acc[0].y : acc[6].y, s1 ? b40.y : b46.y);
    const float cm2 = fmaf(-2.f, s2 ? acc[0].z : acc[6].z, s2 ? b40.z : b46.z);
    const float cm3 = fmaf(-2.f, s3 ? acc[0].w : acc[6].w, s3 ? b40.w : b46.w);
    float mn = min3f(fminf(cm0, cm1), cm2, cm3);
    float mx = max3f(fmaxf(cm0, cm1), cm2, cm3);

    f32x2 m2P; m2P.x = -2.f; m2P.y = -2.f;
    #pragma unroll
    for (int dq = 1; dq < 6; ++dq) {
      const f32x4 b4 = *(const f32x4*)(&Bs[(p + dq) * 16 + mmb]);
      const f32x2 c01 = pkfma(m2P, lo2(acc[dq]), lo2(b4));
      const f32x2 c23 = pkfma(m2P, hi2(acc[dq]), hi2(b4));
      mn = min3f(mn, c01.x, c01.y);
      mn = min3f(mn, c23.x, c23.y);
      mx = max3f(mx, c01.x, c01.y);
      mx = max3f(mx, c23.x, c23.y);
      acc[dq].x = c01.x; acc[dq].y = c01.y;
      acc[dq].z = c23.x; acc[dq].w = c23.y;
    }
    f32x2 t;
    t = xsw16(mn); mn = fminf(t.x, t.y);
    t = xsw32(mn); mn = fminf(t.x, t.y);
    t = xsw16(mx); mx = fmaxf(t.x, t.y);
    t = xsw32(mx); mx = fmaxf(t.x, t.y);

    const float ralpha = 177.0f * 1.4426950408889634f * fastrcp(Ai + mx);
    const float na   = -ralpha;
    const float base = ralpha * mn;
    f32x2 naP;   naP.x = na;   naP.y = na;
    f32x2 baseP; baseP.x = base; baseP.y = base;
    const float w0_ = fastexp2(fmaf(na, cm0, base));
    const float w1_ = fastexp2(fmaf(na, cm1, base));
    const float w2_ = fastexp2(fmaf(na, cm2, base));
    const float w3_ = fastexp2(fmaf(na, cm3, base));
    float sw0 = w0_, sw1 = w1_, sw2 = w2_, sw3 = w3_;
    float sk0 = kf0 * w0_;
    float sk1 = kf1 * w1_;
    float sk2 = kf2 * w2_;
    float sk3 = kf3 * w3_;
    #pragma unroll
    for (int dq = 1; dq < 6; ++dq) {
      const f32x2 g01 = pkfma(naP, lo2(acc[dq]), baseP);
      const f32x2 g23 = pkfma(naP, hi2(acc[dq]), baseP);
      const float u0 = fastexp2(g01.x);
      const float u1 = fastexp2(g01.y);
      const float u2 = fastexp2(g23.x);
      const float u3 = fastexp2(g23.y);
      sw0 += u0; sw1 += u1; sw2 += u2; sw3 += u3;
      sk0 = fmaf((float)(16 * dq + 0), u0, sk0);
      sk1 = fmaf((float)(16 * dq + 1), u1, sk1);
      sk2 = fmaf((float)(16 * dq + 2), u2, sk2);
      sk3 = fmaf((float)(16 * dq + 3), u3, sk3);
    }
    float sw  = (sw0 + sw1) + (sw2 + sw3);
    float skw = (sk0 + sk1) + (sk2 + sk3);
    float sdw = fmaf(Cbase, sw, -skw);
    t = xsw16(sw);  sw  = t.x + t.y;
    t = xsw16(sdw); sdw = t.x + t.y;
    t = xsw32(sw);  sw  = t.x + t.y;
    t = xsw32(sdw); sdw = t.x + t.y;
    if (gq == 0)
      out[((size_t)bz * IMG_H + h) * IMG_W + w0 + p * 16 + n] = sdw * fastrcp(sw);
  }
}

extern "C" void kernel_launch(void* const* d_in, const int* in_sizes, int n_in,
                              void* d_out, int out_size, void* d_ws, size_t ws_size,
                              hipStream_t stream) {
  (void)in_sizes; (void)n_in; (void)out_size; (void)ws_size;
  const float* xl   = (const float*)d_in[0];
  const float* xr   = (const float*)d_in[1];
  const float* Wt   = (const float*)d_in[2];
  const float* bias = (const float*)d_in[3];
  _Float16* Fc = (_Float16*)d_ws;   // conv features [4,192,640,32] f16 = 31.5 MB
  float* out = (float*)d_out;       // [2,384,1280] f32

  hipLaunchKernelGGL(conv_mfma_kernel, dim3(5, 96, 4), dim3(256), 0, stream,
                     xl, xr, Wt, bias, Fc);
  hipLaunchKernelGGL(disparity_mfma_kernel, dim3(IMG_W / TW, IMG_H, 2), dim3(256), 0, stream,
                     Fc, out);
}

// Round 15
// 65.249 us; speedup vs baseline: 1.1867x; 1.0933x over previous
//
#include <hip/hip_runtime.h>
#include <cstddef>

typedef _Float16 h2    __attribute__((ext_vector_type(2)));
typedef _Float16 half4 __attribute__((ext_vector_type(4)));
typedef _Float16 half8 __attribute__((ext_vector_type(8)));
typedef float    f32x4 __attribute__((ext_vector_type(4)));
typedef float    f32x2 __attribute__((ext_vector_type(2)));

#define CH    192
#define CWID  640
#define IMG_H 384
#define IMG_W 1280
#define TW    128
#define GR    224      // g rows staged
#define RAWC  179      // 66 fl cols + 113 g cols
#define RAWP  192

__device__ __forceinline__ float fastrcp(float x) {
#if __has_builtin(__builtin_amdgcn_rcpf)
  return __builtin_amdgcn_rcpf(x);
#else
  return 1.0f / x;
#endif
}
__device__ __forceinline__ float fastexp2(float x) {
#if __has_builtin(__builtin_amdgcn_exp2f)
  return __builtin_amdgcn_exp2f(x);
#else
  return exp2f(x);
#endif
}
__device__ __forceinline__ f32x2 xsw16(float x) {
#if __has_builtin(__builtin_amdgcn_permlane16_swap)
  auto r = __builtin_amdgcn_permlane16_swap(__float_as_uint(x), __float_as_uint(x), false, false);
  f32x2 o; o.x = __uint_as_float(r[0]); o.y = __uint_as_float(r[1]); return o;
#else
  f32x2 o; o.x = x;
  o.y = __uint_as_float((unsigned)__builtin_amdgcn_ds_swizzle((int)__float_as_uint(x), 0x401F));
  return o;
#endif
}
__device__ __forceinline__ f32x2 xsw32(float x) {
#if __has_builtin(__builtin_amdgcn_permlane32_swap)
  auto r = __builtin_amdgcn_permlane32_swap(__float_as_uint(x), __float_as_uint(x), false, false);
  f32x2 o; o.x = __uint_as_float(r[0]); o.y = __uint_as_float(r[1]); return o;
#else
  const int bpa = ((threadIdx.x & 63) ^ 32) << 2;
  f32x2 o; o.x = x;
  o.y = __uint_as_float((unsigned)__builtin_amdgcn_ds_bpermute(bpa, (int)__float_as_uint(x)));
  return o;
#endif
}
__device__ __forceinline__ f32x2 pkfma(f32x2 a, f32x2 b, f32x2 c) {
  f32x2 d; asm("v_pk_fma_f32 %0, %1, %2, %3" : "=v"(d) : "v"(a), "v"(b), "v"(c)); return d;
}
__device__ __forceinline__ float min3f(float a, float b, float c) {
  float d; asm("v_min3_f32 %0, %1, %2, %3" : "=v"(d) : "v"(a), "v"(b), "v"(c)); return d;
}
__device__ __forceinline__ float max3f(float a, float b, float c) {
  float d; asm("v_max3_f32 %0, %1, %2, %3" : "=v"(d) : "v"(a), "v"(b), "v"(c)); return d;
}
__device__ __forceinline__ f32x2 lo2(f32x4 v) { f32x2 r; r.x = v.x; r.y = v.y; return r; }
__device__ __forceinline__ f32x2 hi2(f32x4 v) { f32x2 r; r.x = v.z; r.y = v.w; return r; }

// ---------------- Kernel 1: conv as MFMA GEMM, fragments direct from lin ----------------
// K-permutation: kappa-slice q<3 = row q elements j=0..7; slice 3 = {row0[8],row1[8],
// row2[8],0*5}. W staged with the SAME permutation -> dot product identical (in-MFMA
// k-order rounding ~1e-6, invisible under f16 feature quantum). No Ph/Pl LDS, single
// barrier, LDS 19.8KB -> 8 blocks/CU. Revert path: R14 conv (im2col) / R9 scalar conv.
__global__ __launch_bounds__(256)
void conv_mfma_kernel(const float* __restrict__ xl, const float* __restrict__ xr,
                      const float* __restrict__ Wt, const float* __restrict__ bias,
                      _Float16* __restrict__ Fc) {
  __shared__ alignas(16) float lin[5 * 776];        // 15.5 KB input tile f32
  __shared__ alignas(16) _Float16 Wh[32 * 32];      // 2 KB  W hi [ch][kappa]
  __shared__ alignas(16) _Float16 Wl[32 * 32];      // 2 KB  W lo
  __shared__ float bl[32];

  const int tid = threadIdx.x;
  const int bx = blockIdx.x;        // 0..4  (128-ow tiles)
  const int by = blockIdx.y;        // 0..95 (oh pairs)
  const int bb = blockIdx.z;        // 0..3
  const float* src = (bb < 2) ? (xl + (size_t)bb * (IMG_H * IMG_W * 3))
                              : (xr + (size_t)(bb - 2) * (IMG_H * IMG_W * 3));

  // ---- stage 5 input rows x 774 floats (258 cols x 3ch), coalesced, zero-pad ----
  const int fbase = bx * 768;
  #pragma unroll
  for (int r = 0; r < 5; ++r) {
    const int ir = by * 4 + r;
    const float* grow = src + (size_t)ir * 3840;
    #pragma unroll
    for (int j = 0; j < 2; ++j) {
      const int pr = tid + j * 256;
      if (pr < 388) {
        const int fo = fbase + 2 * pr;
        float2 v; v.x = 0.f; v.y = 0.f;
        if (ir < IMG_H && fo < 3840) v = *(const float2*)(grow + fo);
        *(float2*)(&lin[r * 776 + 2 * pr]) = v;
      }
    }
  }
  // ---- stage W to [ch][kappa=32], hi/lo split, kappa->k permutation ----
  if (tid < 128) {
    const int ch = tid >> 2, q = tid & 3;
    half8 hv, lv;
    #pragma unroll
    for (int e = 0; e < 8; ++e) {
      const int k = (q < 3) ? (q * 9 + e) : ((e < 3) ? (9 * e + 8) : 99);
      const float v = (k < 27) ? Wt[k * 32 + ch] : 0.f;
      const _Float16 hh = (_Float16)v;
      hv[e] = hh;
      lv[e] = (_Float16)(v - (float)hh);
    }
    const int off = ch * 32 + ((q ^ ((ch >> 1) & 3)) << 3);
    *(half8*)(&Wh[off]) = hv;
    *(half8*)(&Wl[off]) = lv;
  }
  if (tid < 32) bl[tid] = bias[tid];
  __syncthreads();

  // ---- fragments + MFMA: D[m=ch][n=px]; per wave 4 px-tiles x 2 ch-tiles ----
  const int lane = tid & 63, wv = tid >> 6;
  const int n  = lane & 15;
  const int gq = lane >> 4;
  const int fs = (gq ^ ((n >> 1) & 3)) << 3;
  const half8 wh0 = *(const half8*)(&Wh[n * 32 + fs]);
  const half8 wl0 = *(const half8*)(&Wl[n * 32 + fs]);
  const half8 wh1 = *(const half8*)(&Wh[(16 + n) * 32 + fs]);
  const half8 wl1 = *(const half8*)(&Wl[(16 + n) * 32 + fs]);
  const float bb0 = bl[gq * 4 + 0], bb1 = bl[gq * 4 + 1];
  const float bb2 = bl[gq * 4 + 2], bb3 = bl[gq * 4 + 3];
  const float bc0 = bl[16 + gq * 4 + 0], bc1 = bl[16 + gq * 4 + 1];
  const float bc2 = bl[16 + gq * 4 + 2], bc3 = bl[16 + gq * 4 + 3];

  const int doh = wv >> 1;                 // px>>7 for this wave
  const int dowb = (wv & 1) * 64 + n;      // dow = dowb + t*16
  const bool g3 = (gq == 3);
  const int rsel = g3 ? 0 : gq;            // vector-read row (gq3 -> broadcast with gq0)

  #pragma unroll
  for (int t = 0; t < 4; ++t) {
    const int dow = dowb + t * 16;
    const int lb = (doh * 2) * 776 + 6 * dow;        // row0 base for this px
    const int vb = lb + rsel * 776;
    // slice elements: q<3 -> 8 contiguous floats of row q (8B-aligned b64 reads);
    // q=3 -> j=8 scalars of rows 0,1,2 (+5 zeros). Same-addr dups broadcast.
    const float2 fa = *(const float2*)(&lin[vb + 0]);
    const float2 fb = *(const float2*)(&lin[vb + 2]);
    const float2 fc = *(const float2*)(&lin[vb + 4]);
    const float2 fd = *(const float2*)(&lin[vb + 6]);
    const float s0 = lin[lb + 8];
    const float s1 = lin[lb + 776 + 8];
    const float s2 = lin[lb + 1552 + 8];
    const float v0 = g3 ? s0 : fa.x;
    const float v1 = g3 ? s1 : fa.y;
    const float v2 = g3 ? s2 : fb.x;
    const float v3 = g3 ? 0.f : fb.y;
    const float v4 = g3 ? 0.f : fc.x;
    const float v5 = g3 ? 0.f : fc.y;
    const float v6 = g3 ? 0.f : fd.x;
    const float v7 = g3 ? 0.f : fd.y;
    half8 ph, pl;
    ph[0] = (_Float16)v0; pl[0] = (_Float16)(v0 - (float)ph[0]);
    ph[1] = (_Float16)v1; pl[1] = (_Float16)(v1 - (float)ph[1]);
    ph[2] = (_Float16)v2; pl[2] = (_Float16)(v2 - (float)ph[2]);
    ph[3] = (_Float16)v3; pl[3] = (_Float16)(v3 - (float)ph[3]);
    ph[4] = (_Float16)v4; pl[4] = (_Float16)(v4 - (float)ph[4]);
    ph[5] = (_Float16)v5; pl[5] = (_Float16)(v5 - (float)ph[5]);
    ph[6] = (_Float16)v6; pl[6] = (_Float16)(v6 - (float)ph[6]);
    ph[7] = (_Float16)v7; pl[7] = (_Float16)(v7 - (float)ph[7]);

    f32x4 z0 = {0.f, 0.f, 0.f, 0.f};
    z0 = __builtin_amdgcn_mfma_f32_16x16x32_f16(wh0, pl, z0, 0, 0, 0);
    z0 = __builtin_amdgcn_mfma_f32_16x16x32_f16(wl0, ph, z0, 0, 0, 0);
    z0 = __builtin_amdgcn_mfma_f32_16x16x32_f16(wh0, ph, z0, 0, 0, 0);
    f32x4 z1 = {0.f, 0.f, 0.f, 0.f};
    z1 = __builtin_amdgcn_mfma_f32_16x16x32_f16(wh1, pl, z1, 0, 0, 0);
    z1 = __builtin_amdgcn_mfma_f32_16x16x32_f16(wl1, ph, z1, 0, 0, 0);
    z1 = __builtin_amdgcn_mfma_f32_16x16x32_f16(wh1, ph, z1, 0, 0, 0);

    const int px = wv * 64 + t * 16 + n;
    const int ow = bx * 128 + (px & 127);
    const int oh = by * 2 + (px >> 7);
    _Float16* fp = Fc + ((size_t)(bb * CH + oh) * CWID + ow) * 32 + gq * 4;
    half4 o0, o1;
    o0[0] = (_Float16)fmaxf(z0[0] + bb0, 0.f);
    o0[1] = (_Float16)fmaxf(z0[1] + bb1, 0.f);
    o0[2] = (_Float16)fmaxf(z0[2] + bb2, 0.f);
    o0[3] = (_Float16)fmaxf(z0[3] + bb3, 0.f);
    o1[0] = (_Float16)fmaxf(z1[0] + bc0, 0.f);
    o1[1] = (_Float16)fmaxf(z1[1] + bc1, 0.f);
    o1[2] = (_Float16)fmaxf(z1[2] + bc2, 0.f);
    o1[3] = (_Float16)fmaxf(z1[3] + bc3, 0.f);
    *(half4*)(fp)      = o0;
    *(half4*)(fp + 16) = o1;
  }
}

// ------- Kernel 2: f16 MFMA cost volume + soft-argmin (unchanged from R14) -------
__global__ __launch_bounds__(256, 4)
void disparity_mfma_kernel(const _Float16* __restrict__ Fc, float* __restrict__ out) {
  __shared__ alignas(16) _Float16 raw[RAWP * 16];
  __shared__ alignas(16) _Float16 flH[8 * 512];
  __shared__ alignas(16) _Float16 gH[14 * 512];
  __shared__ alignas(16) float As[TW];
  __shared__ alignas(16) float Bs[GR];

  const int tid = threadIdx.x;
  const int w0  = blockIdx.x * TW;
  const int h   = blockIdx.y;
  const int bz  = blockIdx.z;

  const int hk = h >> 1;
  int r0, r1; float wv0;
  if (h & 1) { r0 = hk; r1 = (hk + 1 > CH - 1) ? CH - 1 : hk + 1; wv0 = 0.75f; }
  else       { r0 = (hk - 1 < 0) ? 0 : hk - 1; r1 = hk;           wv0 = 0.25f; }
  const half8 w0v = (half8)(_Float16)wv0;
  const half8 w1v = (half8)(_Float16)(1.0f - wv0);

  const int vbaseL = (w0 >> 1) + 639;
  const int vbaseR = (w0 >> 1) + 592;

  char* const rawB = (char*)raw;

  const char* const bL0 = (const char*)(Fc + ((size_t)bz * CH + r0) * CWID * 32);
  const char* const bL1 = (const char*)(Fc + ((size_t)bz * CH + r1) * CWID * 32);
  const char* const bR0 = (const char*)(Fc + ((size_t)(bz + 2) * CH + r0) * CWID * 32);
  const char* const bR1 = (const char*)(Fc + ((size_t)(bz + 2) * CH + r1) * CWID * 32);

  const _Float16 h75 = (_Float16)0.75f, h25 = (_Float16)0.25f;
  int a_r0off, a_s0, a_r1off, a_s1, a_swz; half8 a_h0, a_h1; char* a_dst;
  int b_r0off, b_s0, b_r1off, b_s1, b_swz; half8 b_h0, b_h1; char* b_dst;
  {
    const int row = tid;
    const bool isfl = row < TW;
    const int r  = isfl ? row : row - TW;
    const int uv = isfl ? (w0 + r) : (w0 - 95 + r);
    const int uact = uv < 0 ? uv + IMG_W : (uv >= IMG_W ? uv - IMG_W : uv);
    const int up = uv + IMG_W;
    const int vm0 = (up - 1) >> 1;
    int t0 = vm0 - (isfl ? vbaseL : (vbaseR - 66));
    int t1 = t0 + 1;
    if (uact == 0)         t0 = t1;
    if (uact == IMG_W - 1) t1 = t0;
    a_h0 = (half8)((up & 1) ? h75 : h25);
    a_h1 = (half8)((up & 1) ? h25 : h75);
    a_r0off = t0 * 32; a_s0 = (t0 & 1) << 4;
    a_r1off = t1 * 32; a_s1 = (t1 & 1) << 4;
    a_swz = (r >> 1) & 3;
    a_dst = (char*)(isfl ? flH : gH) + (r >> 4) * 1024 + (r & 15) * 64;
  }
  {
    const int row = tid + 256;
    const int r  = row - TW;
    const int uv = w0 - 95 + r;
    const int uact = uv < 0 ? uv + IMG_W : (uv >= IMG_W ? uv - IMG_W : uv);
    const int up = uv + IMG_W;
    const int vm0 = (up - 1) >> 1;
    int t0 = vm0 - (vbaseR - 66);
    int t1 = t0 + 1;
    if (uact == 0)         t0 = t1;
    if (uact == IMG_W - 1) t1 = t0;
    b_h0 = (half8)((up & 1) ? h75 : h25);
    b_h1 = (half8)((up & 1) ? h25 : h75);
    b_r0off = t0 * 32; b_s0 = (t0 & 1) << 4;
    b_r1off = t1 * 32; b_s1 = (t1 & 1) << 4;
    b_swz = (r >> 1) & 3;
    b_dst = (char*)gH + (r >> 4) * 1024 + (r & 15) * 64;
  }

  float sA = 0.f, sB = 0.f;
  #pragma unroll
  for (int half = 0; half < 2; ++half) {
    #pragma unroll
    for (int it = 0; it < 2; ++it) {
      const int task = tid + it * 256;
      if (it == 0 || tid < 128) {
        const int t    = task >> 1;
        const int cpos = task & 1;
        const int tc   = (t > RAWC - 1) ? RAWC - 1 : t;
        const bool isfl = tc < 66;
        int v = isfl ? (vbaseL + tc) : (vbaseR + tc - 66);
        v -= (v >= 640) ? 640 : 0;
        v -= (v >= 640) ? 640 : 0;
        const char* p0 = isfl ? bL0 : bR0;
        const char* p1 = isfl ? bL1 : bR1;
        const int off = (v << 6) + ((half * 2 + cpos) << 4);
        const half8 a0 = *(const half8*)(p0 + off);
        const half8 a1 = *(const half8*)(p1 + off);
        const half8 vv = a0 * w0v + a1 * w1v;
        *(half8*)(rawB + t * 32 + ((cpos ^ (t & 1)) << 4)) = vv;
      }
    }
    __syncthreads();

    #pragma unroll
    for (int cpos = 0; cpos < 2; ++cpos) {
      const int c16 = half * 2 + cpos;
      const int cb  = cpos << 4;
      {
        const half8 a = *(const half8*)(rawB + a_r0off + (cb ^ a_s0));
        const half8 b = *(const half8*)(rawB + a_r1off + (cb ^ a_s1));
        const half8 v = a * a_h0 + b * a_h1;
        #pragma unroll
        for (int e = 0; e < 4; ++e) {
          h2 pe = {v[2 * e], v[2 * e + 1]};
#if __has_builtin(__builtin_amdgcn_fdot2)
          sA = __builtin_amdgcn_fdot2(pe, pe, sA, false);
#else
          sA += (float)pe[0] * (float)pe[0] + (float)pe[1] * (float)pe[1];
#endif
        }
        *(half8*)(a_dst + ((c16 ^ a_swz) << 4)) = v;
      }
      if (tid < TW + GR - 256) {
        const half8 a = *(const half8*)(rawB + b_r0off + (cb ^ b_s0));
        const half8 b = *(const half8*)(rawB + b_r1off + (cb ^ b_s1));
        const half8 v = a * b_h0 + b * b_h1;
        #pragma unroll
        for (int e = 0; e < 4; ++e) {
          h2 pe = {v[2 * e], v[2 * e + 1]};
#if __has_builtin(__builtin_amdgcn_fdot2)
          sB = __builtin_amdgcn_fdot2(pe, pe, sB, false);
#else
          sB += (float)pe[0] * (float)pe[0] + (float)pe[1] * (float)pe[1];
#endif
        }
        *(half8*)(b_dst + ((c16 ^ b_swz) << 4)) = v;
      }
    }
    __syncthreads();
  }
  if (tid < TW) As[tid] = sA; else Bs[tid - TW] = sA;
  if (tid < TW + GR - 256) Bs[tid + 256 - TW] = sB;
  __syncthreads();

  const int lane = tid & 63;
  const int wid  = tid >> 6;
  const int n  = lane & 15;
  const int gq = lane >> 4;
  const int foffB = n * 64 + ((gq ^ ((n >> 1) & 3)) << 4);
  const float Cbase = (float)(95 - 4 * gq + n);

  const int mmb = gq * 4;
  const bool s0 = (mmb + 0) >= n, s1 = (mmb + 1) >= n;
  const bool s2 = (mmb + 2) >= n, s3 = (mmb + 3) >= n;
  const float kf0 = s0 ? 0.f : 96.f;
  const float kf1 = s1 ? 1.f : 97.f;
  const float kf2 = s2 ? 2.f : 98.f;
  const float kf3 = s3 ? 3.f : 99.f;

  #pragma unroll
  for (int pp = 0; pp < 2; ++pp) {
    const int p = wid * 2 + pp;
    const half8 bfrag = *(const half8*)((const char*)flH + p * 1024 + foffB);
    f32x4 acc[7];
    #pragma unroll
    for (int dq = 0; dq < 7; ++dq) {
      const half8 afrag = *(const half8*)((const char*)gH + (p + dq) * 1024 + foffB);
      f32x4 z = {0.f, 0.f, 0.f, 0.f};
      acc[dq] = __builtin_amdgcn_mfma_f32_16x16x32_f16(afrag, bfrag, z, 0, 0, 0);
    }

    const float Ai = As[p * 16 + n];
    const f32x4 b40 = *(const f32x4*)(&Bs[p * 16 + mmb]);
    const f32x4 b46 = *(const f32x4*)(&Bs[(p + 6) * 16 + mmb]);
    const float cm0 = fmaf(-2.f, s0 ? acc[0].x : acc[6].x, s0 ? b40.x : b46.x);
    const float cm1 = fmaf(-2.f, s1 ? acc[0].y : acc[6].y, s1 ? b40.y : b46.y);
    const float cm2 = fmaf(-2.f, s2 ? acc[0].z : acc[6].z, s2 ? b40.z : b46.z);
    const float cm3 = fmaf(-2.f, s3 ? acc[0].w : acc[6].w, s3 ? b40.w : b46.w);
    float mn = min3f(fminf(cm0, cm1), cm2, cm3);
    float mx = max3f(fmaxf(cm0, cm1), cm2, cm3);

    f32x2 m2P; m2P.x = -2.f; m2P.y = -2.f;
    #pragma unroll
    for (int dq = 1; dq < 6; ++dq) {
      const f32x4 b4 = *(const f32x4*)(&Bs[(p + dq) * 16 + mmb]);
      const f32x2 c01 = pkfma(m2P, lo2(acc[dq]), lo2(b4));
      const f32x2 c23 = pkfma(m2P, hi2(acc[dq]), hi2(b4));
      mn = min3f(mn, c01.x, c01.y);
      mn = min3f(mn, c23.x, c23.y);
      mx = max3f(mx, c01.x, c01.y);
      mx = max3f(mx, c23.x, c23.y);
      acc[dq].x = c01.x; acc[dq].y = c01.y;
      acc[dq].z = c23.x; acc[dq].w = c23.y;
    }
    f32x2 t;
    t = xsw16(mn); mn = fminf(t.x, t.y);
    t = xsw32(mn); mn = fminf(t.x, t.y);
    t = xsw16(mx); mx = fmaxf(t.x, t.y);
    t = xsw32(mx); mx = fmaxf(t.x, t.y);

    const float ralpha = 177.0f * 1.4426950408889634f * fastrcp(Ai + mx);
    const float na   = -ralpha;
    const float base = ralpha * mn;
    f32x2 naP;   naP.x = na;   naP.y = na;
    f32x2 baseP; baseP.x = base; baseP.y = base;
    const float w0_ = fastexp2(fmaf(na, cm0, base));
    const float w1_ = fastexp2(fmaf(na, cm1, base));
    const float w2_ = fastexp2(fmaf(na, cm2, base));
    const float w3_ = fastexp2(fmaf(na, cm3, base));
    float sw0 = w0_, sw1 = w1_, sw2 = w2_, sw3 = w3_;
    float sk0 = kf0 * w0_;
    float sk1 = kf1 * w1_;
    float sk2 = kf2 * w2_;
    float sk3 = kf3 * w3_;
    #pragma unroll
    for (int dq = 1; dq < 6; ++dq) {
      const f32x2 g01 = pkfma(naP, lo2(acc[dq]), baseP);
      const f32x2 g23 = pkfma(naP, hi2(acc[dq]), baseP);
      const float u0 = fastexp2(g01.x);
      const float u1 = fastexp2(g01.y);
      const float u2 = fastexp2(g23.x);
      const float u3 = fastexp2(g23.y);
      sw0 += u0; sw1 += u1; sw2 += u2; sw3 += u3;
      sk0 = fmaf((float)(16 * dq + 0), u0, sk0);
      sk1 = fmaf((float)(16 * dq + 1), u1, sk1);
      sk2 = fmaf((float)(16 * dq + 2), u2, sk2);
      sk3 = fmaf((float)(16 * dq + 3), u3, sk3);
    }
    float sw  = (sw0 + sw1) + (sw2 + sw3);
    float skw = (sk0 + sk1) + (sk2 + sk3);
    float sdw = fmaf(Cbase, sw, -skw);
    t = xsw16(sw);  sw  = t.x + t.y;
    t = xsw16(sdw); sdw = t.x + t.y;
    t = xsw32(sw);  sw  = t.x + t.y;
    t = xsw32(sdw); sdw = t.x + t.y;
    if (gq == 0)
      out[((size_t)bz * IMG_H + h) * IMG_W + w0 + p * 16 + n] = sdw * fastrcp(sw);
  }
}

extern "C" void kernel_launch(void* const* d_in, const int* in_sizes, int n_in,
                              void* d_out, int out_size, void* d_ws, size_t ws_size,
                              hipStream_t stream) {
  (void)in_sizes; (void)n_in; (void)out_size; (void)ws_size;
  const float* xl   = (const float*)d_in[0];
  const float* xr   = (const float*)d_in[1];
  const float* Wt   = (const float*)d_in[2];
  const float* bias = (const float*)d_in[3];
  _Float16* Fc = (_Float16*)d_ws;   // conv features [4,192,640,32] f16 = 31.5 MB
  float* out = (float*)d_out;       // [2,384,1280] f32

  hipLaunchKernelGGL(conv_mfma_kernel, dim3(5, 96, 4), dim3(256), 0, stream,
                     xl, xr, Wt, bias, Fc);
  hipLaunchKernelGGL(disparity_mfma_kernel, dim3(IMG_W / TW, IMG_H, 2), dim3(256), 0, stream,
                     Fc, out);
}